// Round 6
// baseline (41637.460 us; speedup 1.0000x reference)
//
#include <hip/hip_runtime.h>
#include <stdint.h>

typedef __attribute__((ext_vector_type(4))) float f32x4;

#define T_STEPS 4096
#define HID 1024
#define NBLK 256

// ---------------------------------------------------------------------------
// Fully fused persistent LSTM, fp32. 256 blocks x 256 threads, 1 block/CU.
// Block b owns hidden units [4b,4b+4) -> 16 gate columns
//   col(c) = (c>>2)*1024 + b*4 + (c&3), c = tid&15.
// Thread (c, s=tid>>4) holds U[64s..64s+64)[col] and W[...][col] in VGPRs.
//
// NO GRID BARRIER. Each step, block b publishes its 4 h-values as a 16 B
// record + a monotonic RELEASE tag (tag[p][b] = t+1, p = t&1). Wave 0 of
// every block polls all 256 tags (4 per lane, relaxed agent loads), then one
// ACQUIRE fence, then loads the 256 records (4 x dwordx4 per lane) into LDS.
// Rendezvous latency (arrival RMW chains, fin flags) is gone; the step
// dependency is carried by exactly the data.
//
// Parity-2 slot safety: block b overwrites rec[p][b] (h_{t-2}) at step t.
// To publish h_t, b consumed all tags >= t (h_{t-1} ready from everyone), so
// every block published h_{t-1}, so every block consumed h_{t-2}. The old
// record's readers are done; HB via their acquire of tag t-1 -> b's release.
// Tags are monotonic (no reset). Poll uses >=.
//
// Workspace: tag[2][256] u32 @ +0 (2 KB, zeroed), rec[2][256][4] f32 @ +4096
// (8 KB, written before read). 12 KB total.
// ---------------------------------------------------------------------------
__global__ __launch_bounds__(256, 1) void lstm_fused(
    const float* __restrict__ x,    // [4096,1024]
    const float* __restrict__ W,    // [1024,4096]
    const float* __restrict__ U,    // [1024,4096]
    const float* __restrict__ bias, // [4096]
    float* __restrict__ out,        // [4096*1024 + 1024 + 1024]
    float* __restrict__ rec,        // [2][256][4] f32
    unsigned int* __restrict__ tag) // [2][256] u32, zeroed
{
    const int tid  = threadIdx.x;
    const int b    = blockIdx.x;
    const int c    = tid & 15;
    const int s    = tid >> 4;
    const int col  = (c >> 2) * 1024 + b * 4 + (c & 3);
    const int lane = tid & 63;
    const int wave = tid >> 6;

    __shared__ __align__(16) float h_lds[16 * 68];     // h[k] at (k>>6)*68+(k&63)
    __shared__ __align__(16) float x_lds[2][16 * 68];
    __shared__ __align__(16) float red[64];
    __shared__ __align__(16) float bias_l[16];

    float Ureg[64], Wreg[64];
    #pragma unroll
    for (int i = 0; i < 64; ++i) {
        const size_t r = (size_t)(s * 64 + i) * 4096 + col;
        Ureg[i] = U[r];
        Wreg[i] = W[r];
    }
    if (tid < 16) bias_l[tid] = bias[col];

    for (int i = tid; i < 16 * 68; i += 256) h_lds[i] = 0.0f;   // h0 = 0
    const int xofs = (tid >> 4) * 68 + (tid & 15) * 4;
    *(f32x4*)&x_lds[0][xofs] = *(const f32x4*)(x + (size_t)tid * 4);
    f32x4 xpre = *(const f32x4*)(x + 1024 + (size_t)tid * 4);
    __syncthreads();

    const int hbase = s * 68;

    // prologue: W.x_0 partial (4 independent FMA chains)
    float acc_x;
    {
        float a0 = 0.f, a1 = 0.f, a2 = 0.f, a3 = 0.f;
        #pragma unroll
        for (int i = 0; i < 16; ++i) {
            f32x4 x4 = *(const f32x4*)&x_lds[0][hbase + 4 * i];
            a0 += x4.x * Wreg[4*i];   a1 += x4.y * Wreg[4*i+1];
            a2 += x4.z * Wreg[4*i+2]; a3 += x4.w * Wreg[4*i+3];
        }
        acc_x = (a0 + a1) + (a2 + a3);
    }

    f32x4 cvec = {0.f, 0.f, 0.f, 0.f};   // cell state (tid0 only)

    for (int t = 0; t < T_STEPS; ++t) {
        const int p   = t & 1;
        const int nxt = (t + 1) & 1;

        // 1: acc = W.x_t (precomputed) + U.h_{t-1}
        float acc;
        {
            float a0 = 0.f, a1 = 0.f, a2 = 0.f, a3 = 0.f;
            #pragma unroll
            for (int i = 0; i < 16; ++i) {
                f32x4 h4 = *(const f32x4*)&h_lds[hbase + 4 * i];
                a0 += h4.x * Ureg[4*i];   a1 += h4.y * Ureg[4*i+1];
                a2 += h4.z * Ureg[4*i+2]; a3 += h4.w * Ureg[4*i+3];
            }
            acc = acc_x + ((a0 + a1) + (a2 + a3));
        }
        // 2: lanes {c, c+16, c+32, c+48} share a column
        acc += __shfl_down(acc, 32);
        acc += __shfl_down(acc, 16);
        if (lane < 16) red[wave * 16 + lane] = acc;

        // rotate x double-buffer: write x_{t+1}, prefetch x_{t+2}
        *(f32x4*)&x_lds[nxt][xofs] = xpre;
        {
            const int tp2 = (t + 2 < T_STEPS) ? (t + 2) : (T_STEPS - 1);
            xpre = *(const f32x4*)(x + (size_t)tp2 * 1024 + tid * 4);
        }
        __syncthreads();   // [S1] red + x_lds[nxt] visible

        // 3: tid0 — gates for the block's 4 hidden units; publish record+tag
        if (tid == 0) {
            f32x4 g0 = {0,0,0,0}, g1 = {0,0,0,0}, g2 = {0,0,0,0}, g3 = {0,0,0,0};
            #pragma unroll
            for (int w = 0; w < 4; ++w) {
                g0 += *(const f32x4*)&red[w * 16 + 0];
                g1 += *(const f32x4*)&red[w * 16 + 4];
                g2 += *(const f32x4*)&red[w * 16 + 8];
                g3 += *(const f32x4*)&red[w * 16 + 12];
            }
            g0 += *(const f32x4*)&bias_l[0];
            g1 += *(const f32x4*)&bias_l[4];
            g2 += *(const f32x4*)&bias_l[8];
            g3 += *(const f32x4*)&bias_l[12];
            f32x4 hvec;
            #pragma unroll
            for (int u = 0; u < 4; ++u) {
                const float iv = 1.0f / (1.0f + __expf(-g0[u]));
                const float fv = 1.0f / (1.0f + __expf(-g1[u]));
                const float gv = tanhf(g2[u]);
                const float ov = 1.0f / (1.0f + __expf(-g3[u]));
                const float cn = fv * cvec[u] + iv * gv;
                cvec[u] = cn;
                hvec[u] = ov * tanhf(cn);
            }
            if (t == T_STEPS - 1) {
                *(f32x4*)(out + (size_t)t * HID + b * 4) = hvec;
                *(f32x4*)(out + (size_t)T_STEPS * HID + b * 4) = hvec;        // h_T
                *(f32x4*)(out + (size_t)T_STEPS * HID + HID + b * 4) = cvec;  // c_T
            } else {
                *(f32x4*)(rec + ((size_t)p * 256 + b) * 4) = hvec;   // 16 B record
                __hip_atomic_store(&tag[p * 256 + b], (unsigned int)(t + 1),
                                   __ATOMIC_RELEASE, __HIP_MEMORY_SCOPE_AGENT);
                *(f32x4*)(out + (size_t)t * HID + b * 4) = hvec;     // off drain path
            }
        }

        // 4: all threads — W.x_{t+1}; overlaps publish drain & channel latency
        {
            float a0 = 0.f, a1 = 0.f, a2 = 0.f, a3 = 0.f;
            #pragma unroll
            for (int i = 0; i < 16; ++i) {
                f32x4 x4 = *(const f32x4*)&x_lds[nxt][hbase + 4 * i];
                a0 += x4.x * Wreg[4*i];   a1 += x4.y * Wreg[4*i+1];
                a2 += x4.z * Wreg[4*i+2]; a3 += x4.w * Wreg[4*i+3];
            }
            acc_x = (a0 + a1) + (a2 + a3);
        }
        if (t == T_STEPS - 1) break;

        // 5: wave 0 — consume all 256 channels for step t (tags >= t+1)
        if (tid < 64) {
            const unsigned int want = (unsigned int)(t + 1);
            const unsigned int* tp = tag + p * 256 + tid * 4;
            for (;;) {
                const unsigned int a0 = __hip_atomic_load(tp + 0, __ATOMIC_RELAXED, __HIP_MEMORY_SCOPE_AGENT);
                const unsigned int a1 = __hip_atomic_load(tp + 1, __ATOMIC_RELAXED, __HIP_MEMORY_SCOPE_AGENT);
                const unsigned int a2 = __hip_atomic_load(tp + 2, __ATOMIC_RELAXED, __HIP_MEMORY_SCOPE_AGENT);
                const unsigned int a3 = __hip_atomic_load(tp + 3, __ATOMIC_RELAXED, __HIP_MEMORY_SCOPE_AGENT);
                if (a0 >= want && a1 >= want && a2 >= want && a3 >= want) break;
                __builtin_amdgcn_s_sleep(1);
            }
            __builtin_amdgcn_fence(__ATOMIC_ACQUIRE, "agent");  // inv L1/L2; order loads
            const f32x4* rp = (const f32x4*)(rec + ((size_t)p * 256 + tid * 4) * 4);
            #pragma unroll
            for (int i = 0; i < 4; ++i) {
                const f32x4 hv = rp[i];
                const int j = tid * 16 + i * 4;   // h indices [j, j+4)
                *(f32x4*)&h_lds[(j >> 6) * 68 + (j & 63)] = hv;
            }
        }
        __syncthreads();   // [S2] h_t staged
    }
}

extern "C" void kernel_launch(void* const* d_in, const int* in_sizes, int n_in,
                              void* d_out, int out_size, void* d_ws, size_t ws_size,
                              hipStream_t stream) {
    const float* x    = (const float*)d_in[0];
    const float* W    = (const float*)d_in[1];
    const float* U    = (const float*)d_in[2];
    const float* bias = (const float*)d_in[3];
    float* out = (float*)d_out;

    // Workspace: tag[2][256] u32 @ +0 (2 KB, zeroed), rec[2][256][4] f32 @ +4096.
    char* ws = (char*)d_ws;
    unsigned int* tg = (unsigned int*)ws;
    float* rec       = (float*)(ws + 4096);

    hipMemsetAsync(tg, 0, 4096, stream);
    lstm_fused<<<NBLK, 256, 0, stream>>>(x, W, U, bias, out, rec, tg);
}

// Round 7
// 18596.703 us; speedup vs baseline: 2.2390x; 2.2390x over previous
//
#include <hip/hip_runtime.h>
#include <stdint.h>

typedef __attribute__((ext_vector_type(4))) float f32x4;
typedef __attribute__((ext_vector_type(4))) unsigned int u32x4;

#define T_STEPS 4096
#define HID 1024
#define NBLK 256

// ---------------------------------------------------------------------------
// Fully fused persistent LSTM, fp32. 256 blocks x 256 threads, 1 block/CU.
// Block b owns hidden units [4b,4b+4) -> 16 gate columns
//   col(c) = (c>>2)*1024 + b*4 + (c&3), c = tid&15.
// Thread (c, s=tid>>4) holds U/W[64s..64s+64)[col] in VGPRs.
//
// Cross-block h-exchange WITHOUT fences: all mailbox traffic uses
// `sc0 sc1` VMEM ops (bypass L1/L2, hit the coherence point directly) —
// the same path agent-scope atomics use, but with NO buffer_wbl2 /
// buffer_inv (round 6 proved those cost ~8 us/step: FETCH_SIZE +157 MB
// from per-step L2 invalidation). Ordering is s_waitcnt vmcnt(0) only:
//   writer: store record (dwordx4 sc0 sc1) -> vmcnt(0) -> store tag
//   reader: poll tag quad (dwordx4 sc0 sc1) -> fetch records -> vmcnt(0)
// Slot parity-2 safety (same proof as r6): block b overwrites rec[p][b]
// (= h_{t-2}) at step t only after consuming all h_{t-1} tags; a consumer's
// record-reads are vmcnt-drained before its own next tag store, so tag
// t-1 visible => its h_{t-2} reads physically completed. Tags monotonic.
//
// Workspace: tag[2][256] u32 @ +0 (2 KB, zeroed), rec[2][256][4] f32 @ +4096.
// ---------------------------------------------------------------------------
__global__ __launch_bounds__(256, 1) void lstm_fused(
    const float* __restrict__ x,    // [4096,1024]
    const float* __restrict__ W,    // [1024,4096]
    const float* __restrict__ U,    // [1024,4096]
    const float* __restrict__ bias, // [4096]
    float* __restrict__ out,        // [4096*1024 + 1024 + 1024]
    float* __restrict__ rec,        // [2][256][4] f32
    unsigned int* __restrict__ tag) // [2][256] u32, zeroed
{
    const int tid  = threadIdx.x;
    const int b    = blockIdx.x;
    const int c    = tid & 15;
    const int s    = tid >> 4;
    const int col  = (c >> 2) * 1024 + b * 4 + (c & 3);
    const int lane = tid & 63;
    const int wave = tid >> 6;

    __shared__ __align__(16) float h_lds[16 * 68];     // h[k] at (k>>6)*68+(k&63)
    __shared__ __align__(16) float x_lds[2][16 * 68];
    __shared__ __align__(16) float red[64];
    __shared__ __align__(16) float bias_l[16];

    float Ureg[64], Wreg[64];
    #pragma unroll
    for (int i = 0; i < 64; ++i) {
        const size_t r = (size_t)(s * 64 + i) * 4096 + col;
        Ureg[i] = U[r];
        Wreg[i] = W[r];
    }
    if (tid < 16) bias_l[tid] = bias[col];

    for (int i = tid; i < 16 * 68; i += 256) h_lds[i] = 0.0f;   // h0 = 0
    const int xofs = (tid >> 4) * 68 + (tid & 15) * 4;
    *(f32x4*)&x_lds[0][xofs] = *(const f32x4*)(x + (size_t)tid * 4);
    f32x4 xpre = *(const f32x4*)(x + 1024 + (size_t)tid * 4);
    __syncthreads();

    const int hbase = s * 68;

    // prologue: W.x_0 partial (4 independent FMA chains)
    float acc_x;
    {
        float b0 = 0.f, b1 = 0.f, b2 = 0.f, b3 = 0.f;
        #pragma unroll
        for (int i = 0; i < 16; ++i) {
            f32x4 x4 = *(const f32x4*)&x_lds[0][hbase + 4 * i];
            b0 += x4.x * Wreg[4*i];   b1 += x4.y * Wreg[4*i+1];
            b2 += x4.z * Wreg[4*i+2]; b3 += x4.w * Wreg[4*i+3];
        }
        acc_x = (b0 + b1) + (b2 + b3);
    }

    float c_reg = 0.0f;   // cell state: lane u of wave 0 tracks unit b*4+(u&3)

    for (int t = 0; t < T_STEPS; ++t) {
        const int p   = t & 1;
        const int nxt = (t + 1) & 1;

        // 1: acc = W.x_t (precomputed) + U.h_{t-1}
        float acc;
        {
            float a0 = 0.f, a1 = 0.f, a2 = 0.f, a3 = 0.f;
            #pragma unroll
            for (int i = 0; i < 16; ++i) {
                f32x4 h4 = *(const f32x4*)&h_lds[hbase + 4 * i];
                a0 += h4.x * Ureg[4*i];   a1 += h4.y * Ureg[4*i+1];
                a2 += h4.z * Ureg[4*i+2]; a3 += h4.w * Ureg[4*i+3];
            }
            acc = acc_x + ((a0 + a1) + (a2 + a3));
        }
        // 2: lanes {c, c+16, c+32, c+48} share a column
        acc += __shfl_down(acc, 32);
        acc += __shfl_down(acc, 16);
        if (lane < 16) red[wave * 16 + lane] = acc;

        // rotate x double-buffer: write x_{t+1}, prefetch x_{t+2}
        *(f32x4*)&x_lds[nxt][xofs] = xpre;
        {
            const int tp2 = (t + 2 < T_STEPS) ? (t + 2) : (T_STEPS - 1);
            xpre = *(const f32x4*)(x + (size_t)tp2 * 1024 + tid * 4);
        }
        __syncthreads();   // [S1] red + x_lds[nxt] visible

        // 3: wave 0 — gate sums, pointwise (4-lane), publish record+tag
        if (wave == 0) {
            const int cc = lane & 15;
            const float gv = red[cc] + red[16 + cc] + red[32 + cc] + red[48 + cc]
                           + bias_l[cc];
            const int u = lane & 3;
            const float gi = __shfl(gv, u);
            const float gf = __shfl(gv, 4 + u);
            const float gg = __shfl(gv, 8 + u);
            const float go = __shfl(gv, 12 + u);
            const float iv = 1.0f / (1.0f + __expf(-gi));
            const float fv = 1.0f / (1.0f + __expf(-gf));
            const float tg = 1.0f - 2.0f / (1.0f + __expf(2.0f * gg));
            const float ov = 1.0f / (1.0f + __expf(-go));
            const float cn = fv * c_reg + iv * tg;
            c_reg = cn;
            const float hn = ov * (1.0f - 2.0f / (1.0f + __expf(2.0f * cn)));
            f32x4 hv, cv;
            hv.x = __shfl(hn, 0); hv.y = __shfl(hn, 1);
            hv.z = __shfl(hn, 2); hv.w = __shfl(hn, 3);
            cv.x = __shfl(cn, 0); cv.y = __shfl(cn, 1);
            cv.z = __shfl(cn, 2); cv.w = __shfl(cn, 3);
            if (t == T_STEPS - 1) {
                if (lane == 0) {
                    *(f32x4*)(out + (size_t)t * HID + b * 4) = hv;
                    *(f32x4*)(out + (size_t)T_STEPS * HID + b * 4) = hv;        // h_T
                    *(f32x4*)(out + (size_t)T_STEPS * HID + HID + b * 4) = cv;  // c_T
                }
            } else if (lane == 0) {
                float* rp = rec + ((size_t)p * 256 + b) * 4;
                unsigned int* tp = tag + p * 256 + b;
                unsigned int want = (unsigned int)(t + 1);
                asm volatile("global_store_dwordx4 %0, %1, off sc0 sc1"
                             :: "v"(rp), "v"(hv) : "memory");
                asm volatile("s_waitcnt vmcnt(0)" ::: "memory");
                asm volatile("global_store_dword %0, %1, off sc0 sc1"
                             :: "v"(tp), "v"(want) : "memory");
                *(f32x4*)(out + (size_t)t * HID + b * 4) = hv;  // plain, off path
            }
        }
        if (t == T_STEPS - 1) break;

        if (wave != 0) {
            // 4a: waves 1-3 — W.x_{t+1} (overlaps wave 0's poll)
            float b0 = 0.f, b1 = 0.f, b2 = 0.f, b3 = 0.f;
            #pragma unroll
            for (int i = 0; i < 16; ++i) {
                f32x4 x4 = *(const f32x4*)&x_lds[nxt][hbase + 4 * i];
                b0 += x4.x * Wreg[4*i];   b1 += x4.y * Wreg[4*i+1];
                b2 += x4.z * Wreg[4*i+2]; b3 += x4.w * Wreg[4*i+3];
            }
            acc_x = (b0 + b1) + (b2 + b3);
        } else {
            // 4b: wave 0 — poll 256 tags (4/lane, one dwordx4), fetch, stage
            const unsigned int want = (unsigned int)(t + 1);
            const unsigned int* tp4 = tag + p * 256 + lane * 4;
            u32x4 tv;
            for (;;) {
                asm volatile("global_load_dwordx4 %0, %1, off sc0 sc1\n\t"
                             "s_waitcnt vmcnt(0)"
                             : "=v"(tv) : "v"(tp4) : "memory");
                if (tv.x >= want && tv.y >= want && tv.z >= want && tv.w >= want)
                    break;
            }
            const float* rp = rec + ((size_t)p * 256 + lane * 4) * 4;
            f32x4 r0, r1, r2, r3;
            asm volatile("global_load_dwordx4 %0, %1, off sc0 sc1" : "=v"(r0) : "v"(rp));
            asm volatile("global_load_dwordx4 %0, %1, off sc0 sc1" : "=v"(r1) : "v"(rp + 4));
            asm volatile("global_load_dwordx4 %0, %1, off sc0 sc1" : "=v"(r2) : "v"(rp + 8));
            asm volatile("global_load_dwordx4 %0, %1, off sc0 sc1" : "=v"(r3) : "v"(rp + 12));
            asm volatile("s_waitcnt vmcnt(0)" ::: "memory");
            const int j = lane * 16;   // h indices [j, j+16)
            *(f32x4*)&h_lds[((j     ) >> 6) * 68 + ((j     ) & 63)] = r0;
            *(f32x4*)&h_lds[((j +  4) >> 6) * 68 + ((j +  4) & 63)] = r1;
            *(f32x4*)&h_lds[((j +  8) >> 6) * 68 + ((j +  8) & 63)] = r2;
            *(f32x4*)&h_lds[((j + 12) >> 6) * 68 + ((j + 12) & 63)] = r3;
        }
        __syncthreads();   // [S2] h_t staged; W.x_{t+1} ready in waves 1-3

        if (wave == 0) {
            // 4c: wave 0's own W.x_{t+1} (runs while waves 1-3 start the dot)
            float b0 = 0.f, b1 = 0.f, b2 = 0.f, b3 = 0.f;
            #pragma unroll
            for (int i = 0; i < 16; ++i) {
                f32x4 x4 = *(const f32x4*)&x_lds[nxt][hbase + 4 * i];
                b0 += x4.x * Wreg[4*i];   b1 += x4.y * Wreg[4*i+1];
                b2 += x4.z * Wreg[4*i+2]; b3 += x4.w * Wreg[4*i+3];
            }
            acc_x = (b0 + b1) + (b2 + b3);
        }
    }
}

extern "C" void kernel_launch(void* const* d_in, const int* in_sizes, int n_in,
                              void* d_out, int out_size, void* d_ws, size_t ws_size,
                              hipStream_t stream) {
    const float* x    = (const float*)d_in[0];
    const float* W    = (const float*)d_in[1];
    const float* U    = (const float*)d_in[2];
    const float* bias = (const float*)d_in[3];
    float* out = (float*)d_out;

    // Workspace: tag[2][256] u32 @ +0 (2 KB, zeroed), rec[2][256][4] f32 @ +4096.
    char* ws = (char*)d_ws;
    unsigned int* tg = (unsigned int*)ws;
    float* rec       = (float*)(ws + 4096);

    hipMemsetAsync(tg, 0, 4096, stream);
    lstm_fused<<<NBLK, 256, 0, stream>>>(x, W, U, bias, out, rec, tg);
}

// Round 8
// 10484.095 us; speedup vs baseline: 3.9715x; 1.7738x over previous
//
#include <hip/hip_runtime.h>
#include <stdint.h>

typedef __attribute__((ext_vector_type(4))) float f32x4;
typedef __attribute__((ext_vector_type(2))) unsigned int u32x2;
typedef __attribute__((ext_vector_type(4))) unsigned int u32x4;

#define T_STEPS 4096
#define HID 1024
#define NBLK 256

static __device__ __forceinline__ float u2f(unsigned int u) {
    union { float f; unsigned int i; } c; c.i = u; return c.f;
}
static __device__ __forceinline__ unsigned int f2u(float f) {
    union { float f; unsigned int i; } c; c.f = f; return c.i;
}

// ---------------------------------------------------------------------------
// Fully fused persistent LSTM, fp32. 256 blocks x 256 threads, 1 block/CU.
// Block b owns hidden units [4b,4b+4) -> 16 gate columns
//   col(c) = (c>>2)*1024 + b*4 + (c&3), c = tid&15.
// Thread (c, s=tid>>4) holds U/W[64s..64s+64)[col] in VGPRs.
//
// SINGLE-HOP mailbox: each h value is published as an 8-byte pair
// {f32 h, u32 tag=t+1} with ONE global_store_dwordx2 sc0 sc1 (8 B aligned
// => single-copy atomic; no vmcnt drain, no separate tag store). Readers
// poll the pairs themselves (2 x dwordx4 sc0 sc1 per thread = 4 pairs);
// tag arrival == data arrival. Round 7 had 3 serialized coherence-point
// round trips per step (record drain -> tag -> record fetch); this has 1.
//
// Parity-2 slot safety: block b overwrites pair[p][j] (h_t -> h_{t+2}) at
// step t+2 only after its poll of ALL h_{t+1} tags succeeded; any block
// publishes h_{t+1} only after ITS loads of h_t completed (data dependency).
// So a reader still wanting h_t implies no block is at t+2 yet. Tags
// monotonic per slot; poll uses >=. Workspace: pair[2][1024] u64 (16 KB).
//
// out rows 0..4094: written by rotating block (t & 255) as one coalesced
// 4 KB row straight from poll registers (kills the 4-blocks-per-64B-line
// cross-XCD writeback ping-pong seen as WRITE_SIZE=96MB for 16.8MB output).
// Row 4095 + h_T + c_T: per-block lanes 0-3 at the final step.
// ---------------------------------------------------------------------------
__global__ __launch_bounds__(256, 1) void lstm_fused(
    const float* __restrict__ x,    // [4096,1024]
    const float* __restrict__ W,    // [1024,4096]
    const float* __restrict__ U,    // [1024,4096]
    const float* __restrict__ bias, // [4096]
    float* __restrict__ out,        // [4096*1024 + 1024 + 1024]
    unsigned long long* __restrict__ pairs) // [2][1024] {f32,u32}, zeroed
{
    const int tid  = threadIdx.x;
    const int b    = blockIdx.x;
    const int c    = tid & 15;
    const int s    = tid >> 4;
    const int col  = (c >> 2) * 1024 + b * 4 + (c & 3);
    const int lane = tid & 63;
    const int wave = tid >> 6;

    __shared__ __align__(16) float h_lds[16 * 68];     // h[k] at (k>>6)*68+(k&63)
    __shared__ __align__(16) float x_lds[2][16 * 68];
    __shared__ __align__(16) float red[64];
    __shared__ __align__(16) float bias_l[16];

    float Ureg[64], Wreg[64];
    #pragma unroll
    for (int i = 0; i < 64; ++i) {
        const size_t r = (size_t)(s * 64 + i) * 4096 + col;
        Ureg[i] = U[r];
        Wreg[i] = W[r];
    }
    if (tid < 16) bias_l[tid] = bias[col];

    for (int i = tid; i < 16 * 68; i += 256) h_lds[i] = 0.0f;   // h0 = 0
    const int xofs = (tid >> 4) * 68 + (tid & 15) * 4;
    *(f32x4*)&x_lds[0][xofs] = *(const f32x4*)(x + (size_t)tid * 4);
    f32x4 xpre = *(const f32x4*)(x + 1024 + (size_t)tid * 4);
    __syncthreads();

    const int hbase = s * 68;
    const int hofs  = ((tid * 4) >> 6) * 68 + ((tid * 4) & 63);  // stage slot

    // prologue: W.x_0 partial (4 independent FMA chains)
    float acc_x;
    {
        float b0 = 0.f, b1 = 0.f, b2 = 0.f, b3 = 0.f;
        #pragma unroll
        for (int i = 0; i < 16; ++i) {
            f32x4 x4 = *(const f32x4*)&x_lds[0][hbase + 4 * i];
            b0 += x4.x * Wreg[4*i];   b1 += x4.y * Wreg[4*i+1];
            b2 += x4.z * Wreg[4*i+2]; b3 += x4.w * Wreg[4*i+3];
        }
        acc_x = (b0 + b1) + (b2 + b3);
    }

    float c_reg = 0.0f;   // cell state: wave-0 lane u tracks unit b*4+(u&3)

    for (int t = 0; t < T_STEPS; ++t) {
        const int p   = t & 1;
        const int nxt = (t + 1) & 1;

        // 1: acc = W.x_t (precomputed) + U.h_{t-1}
        float acc;
        {
            float a0 = 0.f, a1 = 0.f, a2 = 0.f, a3 = 0.f;
            #pragma unroll
            for (int i = 0; i < 16; ++i) {
                f32x4 h4 = *(const f32x4*)&h_lds[hbase + 4 * i];
                a0 += h4.x * Ureg[4*i];   a1 += h4.y * Ureg[4*i+1];
                a2 += h4.z * Ureg[4*i+2]; a3 += h4.w * Ureg[4*i+3];
            }
            acc = acc_x + ((a0 + a1) + (a2 + a3));
        }
        // 2: lanes {c, c+16, c+32, c+48} share a column
        acc += __shfl_down(acc, 32);
        acc += __shfl_down(acc, 16);
        if (lane < 16) red[wave * 16 + lane] = acc;

        // rotate x double-buffer: write x_{t+1}, prefetch x_{t+2}
        *(f32x4*)&x_lds[nxt][xofs] = xpre;
        {
            const int tp2 = (t + 2 < T_STEPS) ? (t + 2) : (T_STEPS - 1);
            xpre = *(const f32x4*)(x + (size_t)tp2 * 1024 + tid * 4);
        }
        __syncthreads();   // [S1] red + x_lds[nxt] visible

        // 3: wave 0 — gates; lanes 0-3 publish {h, t+1} pairs (one store each)
        if (wave == 0) {
            const int cc = lane & 15;
            const float gv = red[cc] + red[16 + cc] + red[32 + cc] + red[48 + cc]
                           + bias_l[cc];
            const int u = lane & 3;
            const float gi = __shfl(gv, u);
            const float gf = __shfl(gv, 4 + u);
            const float gg = __shfl(gv, 8 + u);
            const float go = __shfl(gv, 12 + u);
            const float iv = 1.0f / (1.0f + __expf(-gi));
            const float fv = 1.0f / (1.0f + __expf(-gf));
            const float tg = 1.0f - 2.0f / (1.0f + __expf(2.0f * gg));
            const float ov = 1.0f / (1.0f + __expf(-go));
            const float cn = fv * c_reg + iv * tg;
            c_reg = cn;
            const float hn = ov * (1.0f - 2.0f / (1.0f + __expf(2.0f * cn)));
            if (t == T_STEPS - 1) {
                if (lane < 4) {
                    out[(size_t)t * HID + b * 4 + lane] = hn;               // row 4095
                    out[(size_t)T_STEPS * HID + b * 4 + lane] = hn;         // h_T
                    out[(size_t)T_STEPS * HID + HID + b * 4 + lane] = cn;   // c_T
                }
            } else if (lane < 4) {
                u32x2 pr;
                pr.x = f2u(hn);
                pr.y = (unsigned int)(t + 1);
                unsigned long long* pp = pairs + (size_t)p * 1024 + b * 4 + lane;
                asm volatile("global_store_dwordx2 %0, %1, off sc0 sc1"
                             :: "v"(pp), "v"(pr) : "memory");
            }
        }
        if (t == T_STEPS - 1) break;

        // 4: all threads — W.x_{t+1} (local work first, then wait)
        {
            float b0 = 0.f, b1 = 0.f, b2 = 0.f, b3 = 0.f;
            #pragma unroll
            for (int i = 0; i < 16; ++i) {
                f32x4 x4 = *(const f32x4*)&x_lds[nxt][hbase + 4 * i];
                b0 += x4.x * Wreg[4*i];   b1 += x4.y * Wreg[4*i+1];
                b2 += x4.z * Wreg[4*i+2]; b3 += x4.w * Wreg[4*i+3];
            }
            acc_x = (b0 + b1) + (b2 + b3);
        }

        // 5: every thread polls its 4 pairs (h indices tid*4 .. tid*4+3)
        {
            const unsigned int want = (unsigned int)(t + 1);
            const unsigned long long* pp = pairs + (size_t)p * 1024 + tid * 4;
            u32x4 q0, q1;
            for (;;) {
                asm volatile("global_load_dwordx4 %0, %2, off sc0 sc1\n\t"
                             "global_load_dwordx4 %1, %3, off sc0 sc1\n\t"
                             "s_waitcnt vmcnt(0)"
                             : "=&v"(q0), "=&v"(q1)
                             : "v"(pp), "v"(pp + 2) : "memory");
                if (q0.y >= want && q0.w >= want && q1.y >= want && q1.w >= want)
                    break;
            }
            f32x4 hv4;
            hv4.x = u2f(q0.x); hv4.y = u2f(q0.z);
            hv4.z = u2f(q1.x); hv4.w = u2f(q1.z);
            // rotating writer: block (t & 255) emits the full coalesced row t
            if (b == (t & 255))
                *(f32x4*)(out + (size_t)t * HID + tid * 4) = hv4;
            *(f32x4*)&h_lds[hofs] = hv4;   // stage h_t
        }
        __syncthreads();   // [S2] h_t staged
    }
}

extern "C" void kernel_launch(void* const* d_in, const int* in_sizes, int n_in,
                              void* d_out, int out_size, void* d_ws, size_t ws_size,
                              hipStream_t stream) {
    const float* x    = (const float*)d_in[0];
    const float* W    = (const float*)d_in[1];
    const float* U    = (const float*)d_in[2];
    const float* bias = (const float*)d_in[3];
    float* out = (float*)d_out;

    // Workspace: pairs[2][1024] x 8 B = 16 KB @ +0 (zeroed: tag fields must
    // start below 1; re-poisoned 0xAA would read as huge tags).
    unsigned long long* pairs = (unsigned long long*)d_ws;

    hipMemsetAsync(pairs, 0, 2 * 1024 * sizeof(unsigned long long), stream);
    lstm_fused<<<NBLK, 256, 0, stream>>>(x, W, U, bias, out, pairs);
}